// Round 6
// baseline (145.023 us; speedup 1.0000x reference)
//
#include <hip/hip_runtime.h>
#include <math.h>

#define CHUNK 512   // rows per block; SL=2048 -> 4 chunks, SS=512 -> 1 chunk

typedef float f4 __attribute__((ext_vector_type(4)));   // clang vector: OK for nontemporal builtins

// Uniform-work kernel. 4 lanes cooperate on one row (4 x float4 each).
// Each thread processes 2 rows per iteration. Register double-buffered:
// iteration k+1's loads are issued before iteration k's compute, so the
// vmcnt wait lands after ~300 cycles of FMA work instead of immediately.
__global__ __launch_bounds__(256) void cosine_chunk_kernel(
    const float* __restrict__ item,
    const float* __restrict__ seqL, const int* __restrict__ indL,
    const float* __restrict__ seqS, const int* __restrict__ indS,
    float* __restrict__ cosL, float* __restrict__ cosS,
    int* __restrict__ histG,
    int B, int SL, int SS, int nbL, int nbS, int nchL)
{
    const int blk = (int)blockIdx.x;
    const bool isLong = blk < B * nchL;
    const int b     = isLong ? (blk / nchL) : (blk - B * nchL);
    const int chunk = isLong ? (blk % nchL) : 0;
    const int S     = isLong ? SL : SS;
    const int nb    = isLong ? nbL : nbS;
    const int bias  = (nb - 2) / 2;          // 22 -> 10, 42 -> 20
    const float scale = (float)bias;         // exactly 1/eps
    const int job   = isLong ? b : B + b;    // global hist row
    const float* __restrict__ seq = isLong ? seqL : seqS;
    const int*   __restrict__ ind = isLong ? indL : indS;
    float* __restrict__ cosOut = isLong ? cosL : cosS;

    const int tid = threadIdx.x;
    __shared__ float item_n[64];
    __shared__ int   hist[64];

    if (tid < 64) {
        float v = item[(size_t)b * 64 + tid];
        float sq = v * v;
        #pragma unroll
        for (int off = 32; off >= 1; off >>= 1)
            sq += __shfl_xor(sq, off, 64);
        item_n[tid] = v * (1.0f / (sqrtf(sq) + 1e-8f));
        hist[tid] = 0;
    }
    __syncthreads();

    const int lane4 = tid & 3;               // float4 slot phase within row
    const int rowId = tid >> 2;              // 0..63: row offset within group
    const f4* __restrict__ item4 = reinterpret_cast<const f4*>(item_n);
    const f4 i0 = item4[0 * 4 + lane4];
    const f4 i1 = item4[1 * 4 + lane4];
    const f4 i2 = item4[2 * 4 + lane4];
    const f4 i3 = item4[3 * 4 + lane4];

    const f4* __restrict__ seqb = reinterpret_cast<const f4*>(seq) + (size_t)b * S * 16;
    const int*    __restrict__ indb = ind    + (size_t)b * S;
    float*        __restrict__ cosb = cosOut + (size_t)b * S;

    const int rowBeg = chunk * CHUNK;        // CHUNK divisible by 128
    const int rowEnd = rowBeg + CHUNK;

    // ---- prologue: load iteration 0 ----
    const f4* P = seqb + (size_t)(rowBeg + rowId) * 16 + lane4;
    f4 a0 = __builtin_nontemporal_load(P + 0);
    f4 a1 = __builtin_nontemporal_load(P + 4);
    f4 a2 = __builtin_nontemporal_load(P + 8);
    f4 a3 = __builtin_nontemporal_load(P + 12);
    f4 b0 = __builtin_nontemporal_load(P + 1024);
    f4 b1 = __builtin_nontemporal_load(P + 1028);
    f4 b2 = __builtin_nontemporal_load(P + 1032);
    f4 b3 = __builtin_nontemporal_load(P + 1036);
    int iv0 = 1, iv1 = 1;
    if (lane4 == 0) { iv0 = indb[rowBeg + rowId]; iv1 = indb[rowBeg + rowId + 64]; }

    #pragma unroll
    for (int base = rowBeg; base < rowEnd; base += 128) {
        // ---- issue next iteration's loads (clamped on last trip) ----
        const int nbase = (base + 128 < rowEnd) ? base + 128 : rowBeg;
        const f4* Pn = seqb + (size_t)(nbase + rowId) * 16 + lane4;
        f4 na0 = __builtin_nontemporal_load(Pn + 0);
        f4 na1 = __builtin_nontemporal_load(Pn + 4);
        f4 na2 = __builtin_nontemporal_load(Pn + 8);
        f4 na3 = __builtin_nontemporal_load(Pn + 12);
        f4 nb0 = __builtin_nontemporal_load(Pn + 1024);
        f4 nb1 = __builtin_nontemporal_load(Pn + 1028);
        f4 nb2 = __builtin_nontemporal_load(Pn + 1032);
        f4 nb3 = __builtin_nontemporal_load(Pn + 1036);
        int niv0 = 1, niv1 = 1;
        if (lane4 == 0) { niv0 = indb[nbase + rowId]; niv1 = indb[nbase + rowId + 64]; }

        // ---- compute iteration k ----
        float dot0 = i0.x*a0.x + i0.y*a0.y + i0.z*a0.z + i0.w*a0.w
                   + i1.x*a1.x + i1.y*a1.y + i1.z*a1.z + i1.w*a1.w
                   + i2.x*a2.x + i2.y*a2.y + i2.z*a2.z + i2.w*a2.w
                   + i3.x*a3.x + i3.y*a3.y + i3.z*a3.z + i3.w*a3.w;
        float sq0  = a0.x*a0.x + a0.y*a0.y + a0.z*a0.z + a0.w*a0.w
                   + a1.x*a1.x + a1.y*a1.y + a1.z*a1.z + a1.w*a1.w
                   + a2.x*a2.x + a2.y*a2.y + a2.z*a2.z + a2.w*a2.w
                   + a3.x*a3.x + a3.y*a3.y + a3.z*a3.z + a3.w*a3.w;
        float dot1 = i0.x*b0.x + i0.y*b0.y + i0.z*b0.z + i0.w*b0.w
                   + i1.x*b1.x + i1.y*b1.y + i1.z*b1.z + i1.w*b1.w
                   + i2.x*b2.x + i2.y*b2.y + i2.z*b2.z + i2.w*b2.w
                   + i3.x*b3.x + i3.y*b3.y + i3.z*b3.z + i3.w*b3.w;
        float sq1  = b0.x*b0.x + b0.y*b0.y + b0.z*b0.z + b0.w*b0.w
                   + b1.x*b1.x + b1.y*b1.y + b1.z*b1.z + b1.w*b1.w
                   + b2.x*b2.x + b2.y*b2.y + b2.z*b2.z + b2.w*b2.w
                   + b3.x*b3.x + b3.y*b3.y + b3.z*b3.z + b3.w*b3.w;

        #pragma unroll
        for (int off = 1; off <= 2; off <<= 1) {
            dot0 += __shfl_xor(dot0, off, 64);
            sq0  += __shfl_xor(sq0,  off, 64);
            dot1 += __shfl_xor(dot1, off, 64);
            sq1  += __shfl_xor(sq1,  off, 64);
        }

        if (lane4 == 0) {
            const int r0 = base + rowId;
            float cos0 = dot0 / (sqrtf(sq0) + 1e-8f);
            if (iv0 <= 0) cos0 = -2.0f;
            __builtin_nontemporal_store(cos0, &cosb[r0]);
            const int id0 = (int)ceilf(cos0 * scale) + bias;
            if (id0 >= 0 && id0 < nb) atomicAdd(&hist[id0], 1);

            float cos1 = dot1 / (sqrtf(sq1) + 1e-8f);
            if (iv1 <= 0) cos1 = -2.0f;
            __builtin_nontemporal_store(cos1, &cosb[r0 + 64]);
            const int id1 = (int)ceilf(cos1 * scale) + bias;
            if (id1 >= 0 && id1 < nb) atomicAdd(&hist[id1], 1);
        }

        // ---- rotate ----
        a0 = na0; a1 = na1; a2 = na2; a3 = na3;
        b0 = nb0; b1 = nb1; b2 = nb2; b3 = nb3;
        iv0 = niv0; iv1 = niv1;
    }
    __syncthreads();

    // Merge block-local histogram into the global per-job histogram.
    if (tid < 64) {
        const int c = hist[tid];
        if (c > 0) atomicAdd(&histG[(size_t)job * 64 + tid], c);
    }
}

// Tiny epilogue: st[b, id*8+j] = log(count+1) * emb[id*8+j]
__global__ __launch_bounds__(64) void simtier_epilogue_kernel(
    const int* __restrict__ histG,
    const float* __restrict__ embL, const float* __restrict__ embS,
    float* __restrict__ stL, float* __restrict__ stS,
    int B, int nbL, int nbS)
{
    const int j = (int)blockIdx.x;           // 0..2B-1
    const bool isLong = j < B;
    const int b  = isLong ? j : j - B;
    const int nb = isLong ? nbL : nbS;
    const float* __restrict__ emb = isLong ? embL : embS;
    float* __restrict__ st = isLong ? stL : stS;
    const int* __restrict__ h = histG + (size_t)j * 64;

    const int nout = nb * 8;
    for (int t = threadIdx.x; t < nout; t += 64) {
        const float c = (float)h[t >> 3];
        st[(size_t)b * nout + t] = logf(c + 1.0f) * emb[t];
    }
}

extern "C" void kernel_launch(void* const* d_in, const int* in_sizes, int n_in,
                              void* d_out, int out_size, void* d_ws, size_t ws_size,
                              hipStream_t stream) {
    const float* item = (const float*)d_in[0];
    const float* seqL = (const float*)d_in[1];
    const float* seqS = (const float*)d_in[2];
    const int*   indL = (const int*)d_in[3];
    const int*   indS = (const int*)d_in[4];
    const float* embL = (const float*)d_in[5];
    const float* embS = (const float*)d_in[6];

    const int B   = in_sizes[0] / 64;
    const int SL  = in_sizes[1] / (B * 64);
    const int SS  = in_sizes[2] / (B * 64);
    const int nbL = in_sizes[5] / 8;   // 22
    const int nbS = in_sizes[6] / 8;   // 42
    const int nchL = SL / CHUNK;       // 4
    const int nchS = SS / CHUNK;       // 1

    float* out  = (float*)d_out;
    float* cosL = out;
    float* cosS = cosL + (size_t)B * SL;
    float* stL  = cosS + (size_t)B * SS;
    float* stS  = stL  + (size_t)B * nbL * 8;

    int* histG = (int*)d_ws;                       // [2B][64] ints
    (void)hipMemsetAsync(histG, 0, (size_t)2 * B * 64 * sizeof(int), stream);

    dim3 grid1(B * nchL + B * nchS), block1(256);
    hipLaunchKernelGGL(cosine_chunk_kernel, grid1, block1, 0, stream,
                       item, seqL, indL, seqS, indS,
                       cosL, cosS, histG, B, SL, SS, nbL, nbS, nchL);

    dim3 grid2(2 * B), block2(64);
    hipLaunchKernelGGL(simtier_epilogue_kernel, grid2, block2, 0, stream,
                       histG, embL, embS, stL, stS, B, nbL, nbS);
}